// Round 6
// baseline (199.665 us; speedup 1.0000x reference)
//
#include <hip/hip_runtime.h>

#define T_TOK 2048
#define D_DIM 512
#define F_DIM 2048
#define E_NUM 8
#define BCAP 2048            // per-expert bucket capacity (worst case: all tokens)
#define LN_EPS 1e-5f

typedef __attribute__((ext_vector_type(8))) short bf16x8;
typedef __attribute__((ext_vector_type(4))) float floatx4;

static __device__ __forceinline__ ushort f2bf(float f) {
  union { float f; unsigned int u; } v; v.f = f;
  unsigned int u = v.u;
  return (ushort)((u + 0x7fffu + ((u >> 16) & 1u)) >> 16);  // RNE
}

static __device__ __forceinline__ void gld_lds16(const void* g, void* l) {
  __builtin_amdgcn_global_load_lds(
      (const __attribute__((address_space(1))) unsigned int*)g,
      (__attribute__((address_space(3))) unsigned int*)l, 16, 0, 0);
}

// ---------------- combined weight transpose+convert (both W1 and W2), zeroes cnt ----------------
// z<8:  W1 f32 [E][D][F] -> W1T bf16 [E][F][D]   (R=512, C=2048)
// z>=8: W2 f32 [E][F][D] -> W2T bf16 [E][D][F]   (R=2048, C=512), (bx,by) remapped
__global__ __launch_bounds__(256) void convT_kernel(
    const float* __restrict__ W1, const float* __restrict__ W2,
    ushort* __restrict__ W1T, ushort* __restrict__ W2T, int* __restrict__ cnt) {
  if (blockIdx.x == 0 && blockIdx.y == 0 && blockIdx.z == 0 && threadIdx.x < E_NUM)
    cnt[threadIdx.x] = 0;  // visible to front_kernel at dispatch boundary
  const float* src; ushort* dst; int R, C, c0, r0;
  if (blockIdx.z < E_NUM) {
    src = W1 + (size_t)blockIdx.z * D_DIM * F_DIM;
    dst = W1T + (size_t)blockIdx.z * D_DIM * F_DIM;
    R = D_DIM; C = F_DIM;
    c0 = blockIdx.x * 64; r0 = blockIdx.y * 32;
  } else {
    src = W2 + (size_t)(blockIdx.z - E_NUM) * D_DIM * F_DIM;
    dst = W2T + (size_t)(blockIdx.z - E_NUM) * D_DIM * F_DIM;
    R = F_DIM; C = D_DIM;
    int idx = blockIdx.y * 32 + blockIdx.x;  // [0,512)
    c0 = (idx & 7) * 64; r0 = (idx >> 3) * 32;
  }
  __shared__ ushort tile[64][34];  // [c][r]
  int tid = threadIdx.x;
  int tc = (tid & 31) * 2, tr = tid >> 5;  // tr in [0,8)
#pragma unroll
  for (int rr = 0; rr < 32; rr += 8) {
    float2 v = *(const float2*)(src + (size_t)(r0 + tr + rr) * C + c0 + tc);
    tile[tc][tr + rr] = f2bf(v.x);
    tile[tc + 1][tr + rr] = f2bf(v.y);
  }
  __syncthreads();
  int wc = tid >> 4, wj = (tid & 15) * 2;
#pragma unroll
  for (int cc = 0; cc < 64; cc += 16) {
    uint v = (uint)tile[cc + wc][wj] | ((uint)tile[cc + wc][wj + 1] << 16);
    *(uint*)(dst + (size_t)(c0 + cc + wc) * R + r0 + wj) = v;
  }
}

// ---------------- fused front: router + bucket-scatter + LN apply ----------------
// One wave per token. Butterfly reduce -> all lanes hold sums. Writes bf16 LN'd
// row into bucket e*BCAP+pos, records tokof/alphav.
__global__ __launch_bounds__(256) void front_kernel(
    const float* __restrict__ x, const float* __restrict__ cent,
    const float* __restrict__ g, const float* __restrict__ b,
    int* __restrict__ cnt, float* __restrict__ alphav,
    int* __restrict__ tokof, ushort* __restrict__ h0p) {
  int wave = threadIdx.x >> 6, lane = threadIdx.x & 63;
  int t = blockIdx.x * 4 + wave;
  const float* xp = x + (size_t)t * D_DIM + lane * 8;
  float4 x0 = *(const float4*)xp, x1 = *(const float4*)(xp + 4);
  float xv[8] = {x0.x, x0.y, x0.z, x0.w, x1.x, x1.y, x1.z, x1.w};
  float s = 0.f, s2 = 0.f, cd[E_NUM];
#pragma unroll
  for (int j = 0; j < 8; j++) { s += xv[j]; s2 += xv[j] * xv[j]; }
#pragma unroll
  for (int e = 0; e < E_NUM; e++) {
    const float* cp = cent + (size_t)e * D_DIM + lane * 8;
    float4 c0 = *(const float4*)cp, c1 = *(const float4*)(cp + 4);
    float cv[8] = {c0.x, c0.y, c0.z, c0.w, c1.x, c1.y, c1.z, c1.w};
    float a = 0.f;
#pragma unroll
    for (int j = 0; j < 8; j++) a += xv[j] * cv[j];
    cd[e] = a;
  }
#pragma unroll
  for (int m = 1; m < 64; m <<= 1) {
    s  += __shfl_xor(s,  m, 64);
    s2 += __shfl_xor(s2, m, 64);
#pragma unroll
    for (int e = 0; e < E_NUM; e++) cd[e] += __shfl_xor(cd[e], m, 64);
  }
  float mu = s / (float)D_DIM;
  float var = s2 / (float)D_DIM - mu * mu;
  if (var < 0.f) var = 0.f;
  float rs = rsqrtf(var + LN_EPS);
  int best = 0;
#pragma unroll
  for (int e = 1; e < E_NUM; e++) if (cd[e] > cd[best]) best = e;  // first-max (np.argmax)
  int pos = 0;
  if (lane == 0) pos = atomicAdd(&cnt[best], 1);
  pos = __shfl(pos, 0, 64);
  if (lane == 0) {
    alphav[t] = 1.f / (1.f + expf(-cd[best]));
    tokof[best * BCAP + pos] = t;
  }
  const float* gp = g + (size_t)best * D_DIM + lane * 8;
  const float* bp = b + (size_t)best * D_DIM + lane * 8;
  union { ushort u16[8]; uint4 v; } o;
#pragma unroll
  for (int j = 0; j < 8; j++)
    o.u16[j] = f2bf((xv[j] - mu) * rs * gp[j] + bp[j]);
  *(uint4*)(h0p + ((size_t)best * BCAP + pos) * D_DIM + lane * 8) = o.v;
}

// ---------------- grouped GEMM (m97 structure + XOR bank swizzle), bucket rows ----------------
// A rows live at bucket e*BCAP + i. BT: [E][NTOT][KTOT] bf16.
// MODE 1: H[bucket] = relu(A*W1 + b1) bf16.      (BM=128, BN=64, KTOT=512)
// MODE 2: out[t] = x[t] + alpha*(A*W2 + b2) f32. (BM=64,  BN=64, KTOT=2048, full-K direct)
// Stale bucket rows may contain garbage/NaN: contaminated acc components are
// row-masked on store (each acc reg component maps to exactly one M-row).
template<int BM, int BN, int KTOT, int NTOT, int MODE>
__global__ __launch_bounds__(256) void moe_gemm_kernel(
    const ushort* __restrict__ A, const ushort* __restrict__ BT,
    const float* __restrict__ bias, const int* __restrict__ cnt,
    const int* __restrict__ tokof, const float* __restrict__ alphav,
    const float* __restrict__ xin, ushort* __restrict__ Hout, float* __restrict__ outF) {
  constexpr int RA = BM / 32, RB = BN / 32;   // staging rounds (32 rows each)
  constexpr int MI = BM / 32, NI = BN / 32;   // 16-wide acc tiles per wave
  constexpr int KITER = KTOT / 64;
  int e = blockIdx.z, mt = blockIdx.y, nt = blockIdx.x;
  int ce = cnt[e];
  if (mt * BM >= ce) return;  // uniform early-exit before any barrier
  int n0 = nt * BN;
  size_t rowbase = (size_t)e * BCAP + mt * BM;

  __shared__ ushort As[BM * 64];  // [m][64], 16B cols XOR-swizzled by (m&7)
  __shared__ ushort Bs[BN * 64];

  int tid = threadIdx.x;
  int lane = tid & 63, wave = tid >> 6;
  int mw = (wave & 1) * (BM / 2), nw = (wave >> 1) * (BN / 2);
  int fm = lane & 15, quad = lane >> 4;
  int fm7 = fm & 7;

  int srow = tid >> 3;                         // [0,32)
  int scol = (((tid & 7) ^ (srow & 7)) * 8);   // swizzled global col (16B units)
  const ushort* a_gp[RA];
  const ushort* b_gp[RB];
#pragma unroll
  for (int r = 0; r < RA; r++)
    a_gp[r] = A + (rowbase + r * 32 + srow) * KTOT + scol;
#pragma unroll
  for (int r = 0; r < RB; r++)
    b_gp[r] = BT + ((size_t)e * NTOT + n0 + r * 32 + srow) * KTOT + scol;
  char* as_l = (char*)As + wave * 1024;  // wave-uniform base (+ r*4096 per round)
  char* bs_l = (char*)Bs + wave * 1024;

  floatx4 acc[MI][NI];
#pragma unroll
  for (int i = 0; i < MI; i++)
#pragma unroll
    for (int j = 0; j < NI; j++) acc[i][j] = (floatx4){0.f, 0.f, 0.f, 0.f};

  for (int ki = 0; ki < KITER; ki++) {
    int k0 = ki * 64;
#pragma unroll
    for (int r = 0; r < RA; r++) gld_lds16(a_gp[r] + k0, as_l + r * 4096);
#pragma unroll
    for (int r = 0; r < RB; r++) gld_lds16(b_gp[r] + k0, bs_l + r * 4096);
    __syncthreads();
#pragma unroll
    for (int ks = 0; ks < 2; ks++) {
      int c8 = ((ks * 4 + quad) ^ fm7) * 8;  // unswizzle on read
      bf16x8 af[MI], bfr[NI];
#pragma unroll
      for (int i = 0; i < MI; i++) af[i]  = *(const bf16x8*)(As + (mw + i * 16 + fm) * 64 + c8);
#pragma unroll
      for (int j = 0; j < NI; j++) bfr[j] = *(const bf16x8*)(Bs + (nw + j * 16 + fm) * 64 + c8);
#pragma unroll
      for (int mi = 0; mi < MI; mi++)
#pragma unroll
        for (int ni = 0; ni < NI; ni++)
          acc[mi][ni] = __builtin_amdgcn_mfma_f32_16x16x32_bf16(af[mi], bfr[ni], acc[mi][ni], 0, 0, 0);
    }
    __syncthreads();
  }

  // C/D layout: col = lane&15, row = quad*4 + reg (m89/m91 verified)
#pragma unroll
  for (int mi = 0; mi < MI; mi++) {
    int lmb = mt * BM + mw + mi * 16 + quad * 4;
#pragma unroll
    for (int r = 0; r < 4; r++) {
      int lm = lmb + r;
      if (lm >= ce) continue;
      if (MODE == 1) {
        size_t row = (size_t)e * BCAP + lm;
#pragma unroll
        for (int ni = 0; ni < NI; ni++) {
          int gcol = n0 + nw + ni * 16 + fm;
          float v = acc[mi][ni][r] + bias[e * NTOT + gcol];
          v = v > 0.f ? v : 0.f;
          Hout[row * NTOT + gcol] = f2bf(v);
        }
      } else {
        int t = tokof[e * BCAP + lm];
        float al = alphav[t];
#pragma unroll
        for (int ni = 0; ni < NI; ni++) {
          int gcol = n0 + nw + ni * 16 + fm;
          outF[(size_t)t * NTOT + gcol] =
              xin[(size_t)t * NTOT + gcol] + al * (acc[mi][ni][r] + bias[e * NTOT + gcol]);
        }
      }
    }
  }
}

extern "C" void kernel_launch(void* const* d_in, const int* in_sizes, int n_in,
                              void* d_out, int out_size, void* d_ws, size_t ws_size,
                              hipStream_t stream) {
  const float* x    = (const float*)d_in[0];
  const float* cent = (const float*)d_in[1];
  const float* ln_g = (const float*)d_in[2];
  const float* ln_b = (const float*)d_in[3];
  const float* W1   = (const float*)d_in[4];
  const float* b1   = (const float*)d_in[5];
  const float* W2   = (const float*)d_in[6];
  const float* b2   = (const float*)d_in[7];
  float* out = (float*)d_out;

  char* ws = (char*)d_ws;
  size_t off = 0;
  auto alloc = [&](size_t bytes) {
    char* p = ws + off;
    off += (bytes + 255) & ~(size_t)255;
    return p;
  };
  int*    cnt    = (int*)alloc(E_NUM * 4);
  float*  alphav = (float*)alloc(T_TOK * 4);
  int*    tokof  = (int*)alloc((size_t)E_NUM * BCAP * 4);               // 64 KB
  ushort* h0p    = (ushort*)alloc((size_t)E_NUM * BCAP * D_DIM * 2);    // 16.8 MB bf16 buckets
  ushort* H      = (ushort*)alloc((size_t)E_NUM * BCAP * F_DIM * 2);    // 67 MB bf16 buckets
  ushort* W1T    = (ushort*)alloc((size_t)E_NUM * F_DIM * D_DIM * 2);   // 16.8 MB bf16 [E][F][D]
  ushort* W2T    = (ushort*)alloc((size_t)E_NUM * D_DIM * F_DIM * 2);   // 16.8 MB bf16 [E][D][F]

  // 1) weight convert/transpose (also zeroes cnt, before front in stream order)
  hipLaunchKernelGGL(convT_kernel, dim3(32, 16, 16), dim3(256), 0, stream,
                     W1, W2, W1T, W2T, cnt);
  // 2) fused router + bucket scatter + LN
  hipLaunchKernelGGL(front_kernel, dim3(T_TOK / 4), dim3(256), 0, stream,
                     x, cent, ln_g, ln_b, cnt, alphav, tokof, h0p);
  // 3) H = relu(h0 @ W1 + b1): 128x64 tiles -> ~512 active blocks (2/CU overlap)
  hipLaunchKernelGGL((moe_gemm_kernel<128, 64, D_DIM, F_DIM, 1>),
                     dim3(F_DIM / 64, BCAP / 128, E_NUM), dim3(256), 0, stream,
                     h0p, W1T, b1, cnt, tokof, alphav, x, H, nullptr);
  // 4) out = x + alpha*(H @ W2 + b2): 64x64 tiles, full K=2048, direct store
  hipLaunchKernelGGL((moe_gemm_kernel<64, 64, F_DIM, D_DIM, 2>),
                     dim3(D_DIM / 64, BCAP / 64, E_NUM), dim3(256), 0, stream,
                     H, W2T, b2, cnt, tokof, alphav, x, nullptr, out);
}

// Round 7
// 191.060 us; speedup vs baseline: 1.0450x; 1.0450x over previous
//
#include <hip/hip_runtime.h>

#define T_TOK 2048
#define D_DIM 512
#define F_DIM 2048
#define E_NUM 8
#define BCAP 2048            // per-expert bucket capacity (worst case: all tokens)
#define LN_EPS 1e-5f

typedef __attribute__((ext_vector_type(8))) short bf16x8;
typedef __attribute__((ext_vector_type(4))) float floatx4;

static __device__ __forceinline__ ushort f2bf(float f) {
  union { float f; unsigned int u; } v; v.f = f;
  unsigned int u = v.u;
  return (ushort)((u + 0x7fffu + ((u >> 16) & 1u)) >> 16);  // RNE
}

static __device__ __forceinline__ void gld_lds16(const void* g, void* l) {
  __builtin_amdgcn_global_load_lds(
      (const __attribute__((address_space(1))) unsigned int*)g,
      (__attribute__((address_space(3))) unsigned int*)l, 16, 0, 0);
}

// ---------------- combined weight transpose+convert (both W1 and W2), zeroes cnt ----------------
// z<8:  W1 f32 [E][D][F] -> W1T bf16 [E][F][D]   (R=512, C=2048)
// z>=8: W2 f32 [E][F][D] -> W2T bf16 [E][D][F]   (R=2048, C=512), (bx,by) remapped
__global__ __launch_bounds__(256) void convT_kernel(
    const float* __restrict__ W1, const float* __restrict__ W2,
    ushort* __restrict__ W1T, ushort* __restrict__ W2T, int* __restrict__ cnt) {
  if (blockIdx.x == 0 && blockIdx.y == 0 && blockIdx.z == 0 && threadIdx.x < E_NUM)
    cnt[threadIdx.x] = 0;  // visible to front_kernel at dispatch boundary
  const float* src; ushort* dst; int R, C, c0, r0;
  if (blockIdx.z < E_NUM) {
    src = W1 + (size_t)blockIdx.z * D_DIM * F_DIM;
    dst = W1T + (size_t)blockIdx.z * D_DIM * F_DIM;
    R = D_DIM; C = F_DIM;
    c0 = blockIdx.x * 64; r0 = blockIdx.y * 32;
  } else {
    src = W2 + (size_t)(blockIdx.z - E_NUM) * D_DIM * F_DIM;
    dst = W2T + (size_t)(blockIdx.z - E_NUM) * D_DIM * F_DIM;
    R = F_DIM; C = D_DIM;
    int idx = blockIdx.y * 32 + blockIdx.x;  // [0,512)
    c0 = (idx & 7) * 64; r0 = (idx >> 3) * 32;
  }
  __shared__ ushort tile[64][34];  // [c][r]
  int tid = threadIdx.x;
  int tc = (tid & 31) * 2, tr = tid >> 5;  // tr in [0,8)
#pragma unroll
  for (int rr = 0; rr < 32; rr += 8) {
    float2 v = *(const float2*)(src + (size_t)(r0 + tr + rr) * C + c0 + tc);
    tile[tc][tr + rr] = f2bf(v.x);
    tile[tc + 1][tr + rr] = f2bf(v.y);
  }
  __syncthreads();
  int wc = tid >> 4, wj = (tid & 15) * 2;
#pragma unroll
  for (int cc = 0; cc < 64; cc += 16) {
    uint v = (uint)tile[cc + wc][wj] | ((uint)tile[cc + wc][wj + 1] << 16);
    *(uint*)(dst + (size_t)(c0 + cc + wc) * R + r0 + wj) = v;
  }
}

// ---------------- fused front: router + bucket-scatter + LN apply + out-init ----------------
// One wave per token. Butterfly reduce -> all lanes hold sums. Writes bf16 LN'd
// row into bucket e*BCAP+pos, records tokof/alphav, and initializes
// out[t] = x[t] + alpha * b2[e]  (GEMM2 atomically accumulates alpha*acc on top).
__global__ __launch_bounds__(256) void front_kernel(
    const float* __restrict__ x, const float* __restrict__ cent,
    const float* __restrict__ g, const float* __restrict__ b,
    const float* __restrict__ b2,
    int* __restrict__ cnt, float* __restrict__ alphav,
    int* __restrict__ tokof, ushort* __restrict__ h0p, float* __restrict__ out) {
  int wave = threadIdx.x >> 6, lane = threadIdx.x & 63;
  int t = blockIdx.x * 4 + wave;
  const float* xp = x + (size_t)t * D_DIM + lane * 8;
  float4 x0 = *(const float4*)xp, x1 = *(const float4*)(xp + 4);
  float xv[8] = {x0.x, x0.y, x0.z, x0.w, x1.x, x1.y, x1.z, x1.w};
  float s = 0.f, s2 = 0.f, cd[E_NUM];
#pragma unroll
  for (int j = 0; j < 8; j++) { s += xv[j]; s2 += xv[j] * xv[j]; }
#pragma unroll
  for (int e = 0; e < E_NUM; e++) {
    const float* cp = cent + (size_t)e * D_DIM + lane * 8;
    float4 c0 = *(const float4*)cp, c1 = *(const float4*)(cp + 4);
    float cv[8] = {c0.x, c0.y, c0.z, c0.w, c1.x, c1.y, c1.z, c1.w};
    float a = 0.f;
#pragma unroll
    for (int j = 0; j < 8; j++) a += xv[j] * cv[j];
    cd[e] = a;
  }
#pragma unroll
  for (int m = 1; m < 64; m <<= 1) {
    s  += __shfl_xor(s,  m, 64);
    s2 += __shfl_xor(s2, m, 64);
#pragma unroll
    for (int e = 0; e < E_NUM; e++) cd[e] += __shfl_xor(cd[e], m, 64);
  }
  float mu = s / (float)D_DIM;
  float var = s2 / (float)D_DIM - mu * mu;
  if (var < 0.f) var = 0.f;
  float rs = rsqrtf(var + LN_EPS);
  int best = 0;
#pragma unroll
  for (int e = 1; e < E_NUM; e++) if (cd[e] > cd[best]) best = e;  // first-max (np.argmax)
  float al = 1.f / (1.f + expf(-cd[best]));
  int pos = 0;
  if (lane == 0) pos = atomicAdd(&cnt[best], 1);
  pos = __shfl(pos, 0, 64);
  if (lane == 0) {
    alphav[t] = al;
    tokof[best * BCAP + pos] = t;
  }
  const float* gp = g + (size_t)best * D_DIM + lane * 8;
  const float* bp = b + (size_t)best * D_DIM + lane * 8;
  union { ushort u16[8]; uint4 v; } o;
#pragma unroll
  for (int j = 0; j < 8; j++)
    o.u16[j] = f2bf((xv[j] - mu) * rs * gp[j] + bp[j]);
  *(uint4*)(h0p + ((size_t)best * BCAP + pos) * D_DIM + lane * 8) = o.v;
  // out init: x + alpha*b2[e]
  const float* b2p = b2 + (size_t)best * D_DIM + lane * 8;
  float ov[8];
#pragma unroll
  for (int j = 0; j < 8; j++) ov[j] = xv[j] + al * b2p[j];
  float* op = out + (size_t)t * D_DIM + lane * 8;
  *(float4*)op = *(const float4*)ov;
  *(float4*)(op + 4) = *(const float4*)(ov + 4);
}

// ---------------- grouped GEMM, 128x128 tile (m97 structure + XOR bank swizzle) ----------------
// A rows live at bucket e*BCAP + i. BT: [E][NTOT][KTOT] bf16. BK=64, 8 k-iters.
// MODE 1: H[bucket] = relu(A*W1 + b1) bf16.  KTOT=512, bx = nt in [0,16).
// MODE 2: out[t] += alpha*acc (atomic, split-K). KTOT=2048, bx = slice*4 + nt, slice k-window 512.
// Stale bucket rows hold finite garbage (0xAA bf16 ~ 3e-13); contaminated acc
// components are row-masked on store (each acc component maps to one M-row).
template<int KTOT, int NTOT, int MODE>
__global__ __launch_bounds__(256) void moe_gemm_kernel(
    const ushort* __restrict__ A, const ushort* __restrict__ BT,
    const float* __restrict__ bias, const int* __restrict__ cnt,
    const int* __restrict__ tokof, const float* __restrict__ alphav,
    ushort* __restrict__ Hout, float* __restrict__ outF) {
  constexpr int KITER = 8;  // 512 k-window per block
  int e = blockIdx.z, mt = blockIdx.y;
  int ce = cnt[e];
  if (mt * 128 >= ce) return;  // uniform early-exit before any barrier
  int bx = blockIdx.x;
  int nt = (MODE == 1) ? bx : (bx & 3);
  int k_base = (MODE == 1) ? 0 : (bx >> 2) * 512;
  int n0 = nt * 128;
  size_t rowbase = (size_t)e * BCAP + mt * 128;

  __shared__ ushort As[128 * 64];  // [m][64], 16B cols XOR-swizzled by (m&7)
  __shared__ ushort Bs[128 * 64];  // [n][64], same swizzle

  int tid = threadIdx.x;
  int lane = tid & 63, wave = tid >> 6;
  int mw = (wave & 1) * 64, nw = (wave >> 1) * 64;  // wave's 64x64 sub-tile
  int fm = lane & 15, quad = lane >> 4;
  int fm7 = fm & 7;

  int srow = tid >> 3;                         // [0,32)
  int scol = (((tid & 7) ^ (srow & 7)) * 8);   // swizzled global col (16B units)
  const ushort* a_gp[4];
  const ushort* b_gp[4];
#pragma unroll
  for (int r = 0; r < 4; r++) {
    a_gp[r] = A + (rowbase + r * 32 + srow) * KTOT + k_base + scol;
    b_gp[r] = BT + ((size_t)e * NTOT + n0 + r * 32 + srow) * KTOT + k_base + scol;
  }
  char* as_l = (char*)As + wave * 1024;  // wave-uniform base (+ r*4096 per round)
  char* bs_l = (char*)Bs + wave * 1024;

  floatx4 acc[4][4];
#pragma unroll
  for (int i = 0; i < 4; i++)
#pragma unroll
    for (int j = 0; j < 4; j++) acc[i][j] = (floatx4){0.f, 0.f, 0.f, 0.f};

  for (int ki = 0; ki < KITER; ki++) {
    int k0 = ki * 64;
#pragma unroll
    for (int r = 0; r < 4; r++) {
      gld_lds16(a_gp[r] + k0, as_l + r * 4096);
      gld_lds16(b_gp[r] + k0, bs_l + r * 4096);
    }
    __syncthreads();
#pragma unroll
    for (int ks = 0; ks < 2; ks++) {
      int c8 = ((ks * 4 + quad) ^ fm7) * 8;  // unswizzle on read
      bf16x8 af[4], bfr[4];
#pragma unroll
      for (int i = 0; i < 4; i++) {
        af[i]  = *(const bf16x8*)(As + (mw + i * 16 + fm) * 64 + c8);
        bfr[i] = *(const bf16x8*)(Bs + (nw + i * 16 + fm) * 64 + c8);
      }
#pragma unroll
      for (int mi = 0; mi < 4; mi++)
#pragma unroll
        for (int ni = 0; ni < 4; ni++)
          acc[mi][ni] = __builtin_amdgcn_mfma_f32_16x16x32_bf16(af[mi], bfr[ni], acc[mi][ni], 0, 0, 0);
    }
    __syncthreads();
  }

  // C/D layout: col = lane&15, row = quad*4 + reg (m89/m91 verified)
#pragma unroll
  for (int mi = 0; mi < 4; mi++) {
    int lmb = mt * 128 + mw + mi * 16 + quad * 4;
#pragma unroll
    for (int r = 0; r < 4; r++) {
      int lm = lmb + r;
      if (lm >= ce) continue;
      if (MODE == 1) {
        size_t row = (size_t)e * BCAP + lm;
#pragma unroll
        for (int ni = 0; ni < 4; ni++) {
          int gcol = n0 + nw + ni * 16 + fm;
          float v = acc[mi][ni][r] + bias[e * NTOT + gcol];
          v = v > 0.f ? v : 0.f;
          Hout[row * NTOT + gcol] = f2bf(v);
        }
      } else {
        int t = tokof[e * BCAP + lm];
        float al = alphav[t];
#pragma unroll
        for (int ni = 0; ni < 4; ni++) {
          int gcol = n0 + nw + ni * 16 + fm;
          atomicAdd(&outF[(size_t)t * NTOT + gcol], al * acc[mi][ni][r]);
        }
      }
    }
  }
}

extern "C" void kernel_launch(void* const* d_in, const int* in_sizes, int n_in,
                              void* d_out, int out_size, void* d_ws, size_t ws_size,
                              hipStream_t stream) {
  const float* x    = (const float*)d_in[0];
  const float* cent = (const float*)d_in[1];
  const float* ln_g = (const float*)d_in[2];
  const float* ln_b = (const float*)d_in[3];
  const float* W1   = (const float*)d_in[4];
  const float* b1   = (const float*)d_in[5];
  const float* W2   = (const float*)d_in[6];
  const float* b2   = (const float*)d_in[7];
  float* out = (float*)d_out;

  char* ws = (char*)d_ws;
  size_t off = 0;
  auto alloc = [&](size_t bytes) {
    char* p = ws + off;
    off += (bytes + 255) & ~(size_t)255;
    return p;
  };
  int*    cnt    = (int*)alloc(E_NUM * 4);
  float*  alphav = (float*)alloc(T_TOK * 4);
  int*    tokof  = (int*)alloc((size_t)E_NUM * BCAP * 4);               // 64 KB
  ushort* h0p    = (ushort*)alloc((size_t)E_NUM * BCAP * D_DIM * 2);    // 16.8 MB bf16 buckets
  ushort* H      = (ushort*)alloc((size_t)E_NUM * BCAP * F_DIM * 2);    // 67 MB bf16 buckets
  ushort* W1T    = (ushort*)alloc((size_t)E_NUM * F_DIM * D_DIM * 2);   // 16.8 MB bf16 [E][F][D]
  ushort* W2T    = (ushort*)alloc((size_t)E_NUM * D_DIM * F_DIM * 2);   // 16.8 MB bf16 [E][D][F]

  // 1) weight convert/transpose (also zeroes cnt, before front in stream order)
  hipLaunchKernelGGL(convT_kernel, dim3(32, 16, 16), dim3(256), 0, stream,
                     W1, W2, W1T, W2T, cnt);
  // 2) fused router + bucket scatter + LN + out-init (x + alpha*b2)
  hipLaunchKernelGGL(front_kernel, dim3(T_TOK / 4), dim3(256), 0, stream,
                     x, cent, ln_g, ln_b, b2, cnt, alphav, tokof, h0p, out);
  // 3) H = relu(h0 @ W1 + b1): 128x128 tiles
  hipLaunchKernelGGL((moe_gemm_kernel<D_DIM, F_DIM, 1>),
                     dim3(F_DIM / 128, BCAP / 128, E_NUM), dim3(256), 0, stream,
                     h0p, W1T, b1, cnt, tokof, alphav, H, nullptr);
  // 4) out += alpha*(H @ W2): 128x128 tiles, split-K=4, atomic accumulate
  hipLaunchKernelGGL((moe_gemm_kernel<F_DIM, D_DIM, 2>),
                     dim3(4 * 4, BCAP / 128, E_NUM), dim3(256), 0, stream,
                     H, W2T, nullptr, cnt, tokof, alphav, nullptr, out);
}

// Round 8
// 180.734 us; speedup vs baseline: 1.1047x; 1.0571x over previous
//
#include <hip/hip_runtime.h>

#define T_TOK 2048
#define D_DIM 512
#define F_DIM 2048
#define E_NUM 8
#define BCAP 2048            // per-expert bucket capacity (worst case: all tokens)
#define LN_EPS 1e-5f

typedef __attribute__((ext_vector_type(8))) short bf16x8;
typedef __attribute__((ext_vector_type(4))) float floatx4;

static __device__ __forceinline__ ushort f2bf(float f) {
  union { float f; unsigned int u; } v; v.f = f;
  unsigned int u = v.u;
  return (ushort)((u + 0x7fffu + ((u >> 16) & 1u)) >> 16);  // RNE
}

static __device__ __forceinline__ void gld_lds16(const void* g, void* l) {
  __builtin_amdgcn_global_load_lds(
      (const __attribute__((address_space(1))) unsigned int*)g,
      (__attribute__((address_space(3))) unsigned int*)l, 16, 0, 0);
}

// ---------------- combined weight transpose+convert (both W1 and W2), zeroes cnt ----------------
__global__ __launch_bounds__(256) void convT_kernel(
    const float* __restrict__ W1, const float* __restrict__ W2,
    ushort* __restrict__ W1T, ushort* __restrict__ W2T, int* __restrict__ cnt) {
  if (blockIdx.x == 0 && blockIdx.y == 0 && blockIdx.z == 0 && threadIdx.x < E_NUM)
    cnt[threadIdx.x] = 0;  // visible to front_kernel at dispatch boundary
  const float* src; ushort* dst; int R, C, c0, r0;
  if (blockIdx.z < E_NUM) {
    src = W1 + (size_t)blockIdx.z * D_DIM * F_DIM;
    dst = W1T + (size_t)blockIdx.z * D_DIM * F_DIM;
    R = D_DIM; C = F_DIM;
    c0 = blockIdx.x * 64; r0 = blockIdx.y * 32;
  } else {
    src = W2 + (size_t)(blockIdx.z - E_NUM) * D_DIM * F_DIM;
    dst = W2T + (size_t)(blockIdx.z - E_NUM) * D_DIM * F_DIM;
    R = F_DIM; C = D_DIM;
    int idx = blockIdx.y * 32 + blockIdx.x;  // [0,512)
    c0 = (idx & 7) * 64; r0 = (idx >> 3) * 32;
  }
  __shared__ ushort tile[64][34];  // [c][r]
  int tid = threadIdx.x;
  int tc = (tid & 31) * 2, tr = tid >> 5;  // tr in [0,8)
#pragma unroll
  for (int rr = 0; rr < 32; rr += 8) {
    float2 v = *(const float2*)(src + (size_t)(r0 + tr + rr) * C + c0 + tc);
    tile[tc][tr + rr] = f2bf(v.x);
    tile[tc + 1][tr + rr] = f2bf(v.y);
  }
  __syncthreads();
  int wc = tid >> 4, wj = (tid & 15) * 2;
#pragma unroll
  for (int cc = 0; cc < 64; cc += 16) {
    uint v = (uint)tile[cc + wc][wj] | ((uint)tile[cc + wc][wj + 1] << 16);
    *(uint*)(dst + (size_t)(c0 + cc + wc) * R + r0 + wj) = v;
  }
}

// ---------------- fused front: router + bucket-scatter + LN apply ----------------
__global__ __launch_bounds__(256) void front_kernel(
    const float* __restrict__ x, const float* __restrict__ cent,
    const float* __restrict__ g, const float* __restrict__ b,
    int* __restrict__ cnt, float* __restrict__ alphav, int* __restrict__ eidv,
    int* __restrict__ tokof, ushort* __restrict__ h0p) {
  int wave = threadIdx.x >> 6, lane = threadIdx.x & 63;
  int t = blockIdx.x * 4 + wave;
  const float* xp = x + (size_t)t * D_DIM + lane * 8;
  float4 x0 = *(const float4*)xp, x1 = *(const float4*)(xp + 4);
  float xv[8] = {x0.x, x0.y, x0.z, x0.w, x1.x, x1.y, x1.z, x1.w};
  float s = 0.f, s2 = 0.f, cd[E_NUM];
#pragma unroll
  for (int j = 0; j < 8; j++) { s += xv[j]; s2 += xv[j] * xv[j]; }
#pragma unroll
  for (int e = 0; e < E_NUM; e++) {
    const float* cp = cent + (size_t)e * D_DIM + lane * 8;
    float4 c0 = *(const float4*)cp, c1 = *(const float4*)(cp + 4);
    float cv[8] = {c0.x, c0.y, c0.z, c0.w, c1.x, c1.y, c1.z, c1.w};
    float a = 0.f;
#pragma unroll
    for (int j = 0; j < 8; j++) a += xv[j] * cv[j];
    cd[e] = a;
  }
#pragma unroll
  for (int m = 1; m < 64; m <<= 1) {
    s  += __shfl_xor(s,  m, 64);
    s2 += __shfl_xor(s2, m, 64);
#pragma unroll
    for (int e = 0; e < E_NUM; e++) cd[e] += __shfl_xor(cd[e], m, 64);
  }
  float mu = s / (float)D_DIM;
  float var = s2 / (float)D_DIM - mu * mu;
  if (var < 0.f) var = 0.f;
  float rs = rsqrtf(var + LN_EPS);
  int best = 0;
#pragma unroll
  for (int e = 1; e < E_NUM; e++) if (cd[e] > cd[best]) best = e;  // first-max (np.argmax)
  int pos = 0;
  if (lane == 0) pos = atomicAdd(&cnt[best], 1);
  pos = __shfl(pos, 0, 64);
  if (lane == 0) {
    alphav[t] = 1.f / (1.f + expf(-cd[best]));
    eidv[t] = best;
    tokof[best * BCAP + pos] = t;
  }
  const float* gp = g + (size_t)best * D_DIM + lane * 8;
  const float* bp = b + (size_t)best * D_DIM + lane * 8;
  union { ushort u16[8]; uint4 v; } o;
#pragma unroll
  for (int j = 0; j < 8; j++)
    o.u16[j] = f2bf((xv[j] - mu) * rs * gp[j] + bp[j]);
  *(uint4*)(h0p + ((size_t)best * BCAP + pos) * D_DIM + lane * 8) = o.v;
}

// ---------------- final reduce: out = x + alpha * (sum of split-K partials + b2) ----------------
__global__ __launch_bounds__(128) void reduce_kernel(
    const float* __restrict__ P, const float* __restrict__ x, const float* __restrict__ b2,
    const int* __restrict__ eidv, const float* __restrict__ alphav,
    float* __restrict__ out) {
  int t = blockIdx.x;
  int e = eidv[t];
  float al = alphav[t];
  int c = threadIdx.x * 4;
  const size_t stride = (size_t)T_TOK * D_DIM;
  float4 s0 = *(const float4*)(P + (size_t)t * D_DIM + c);
  float4 s1 = *(const float4*)(P + stride + (size_t)t * D_DIM + c);
  float4 s2 = *(const float4*)(P + 2 * stride + (size_t)t * D_DIM + c);
  float4 s3 = *(const float4*)(P + 3 * stride + (size_t)t * D_DIM + c);
  float4 bv = *(const float4*)(b2 + (size_t)e * D_DIM + c);
  float4 xv = *(const float4*)(x + (size_t)t * D_DIM + c);
  float4 o;
  o.x = xv.x + al * (s0.x + s1.x + s2.x + s3.x + bv.x);
  o.y = xv.y + al * (s0.y + s1.y + s2.y + s3.y + bv.y);
  o.z = xv.z + al * (s0.z + s1.z + s2.z + s3.z + bv.z);
  o.w = xv.w + al * (s0.w + s1.w + s2.w + s3.w + bv.w);
  *(float4*)(out + (size_t)t * D_DIM + c) = o;
}

// ---------------- grouped GEMM, 128x128 tile, DOUBLE-BUFFERED LDS ----------------
// One barrier per k-iter; DMA(ki+1) issued right after the barrier publishing ki,
// so the vmcnt(0) at the next barrier finds it complete (latency hidden behind
// the MFMA phase). XOR bank swizzle as before (2-way = free, m136).
// MODE 1: H[bucket] = relu(A*W1 + b1) bf16.  KTOT=512, bx = nt in [0,16).
// MODE 2: Part[slice][t] = A*W2 slice-sum (raw). KTOT=2048, bx = slice*4+nt.
template<int KTOT, int NTOT, int MODE>
__global__ __launch_bounds__(256) void moe_gemm_kernel(
    const ushort* __restrict__ A, const ushort* __restrict__ BT,
    const float* __restrict__ bias, const int* __restrict__ cnt,
    const int* __restrict__ tokof,
    ushort* __restrict__ Hout, float* __restrict__ Pout) {
  constexpr int KITER = 8;  // 512 k-window per block
  int e = blockIdx.z, mt = blockIdx.y;
  int ce = cnt[e];
  if (mt * 128 >= ce) return;  // uniform early-exit before any barrier
  int bx = blockIdx.x;
  int nt = (MODE == 1) ? bx : (bx & 3);
  int k_base = (MODE == 1) ? 0 : (bx >> 2) * 512;
  int n0 = nt * 128;
  size_t rowbase = (size_t)e * BCAP + mt * 128;

  __shared__ ushort As[2][128 * 64];  // [buf][m][64], 16B cols XOR-swizzled by (m&7)
  __shared__ ushort Bs[2][128 * 64];

  int tid = threadIdx.x;
  int lane = tid & 63, wave = tid >> 6;
  int mw = (wave & 1) * 64, nw = (wave >> 1) * 64;  // wave's 64x64 sub-tile
  int fm = lane & 15, quad = lane >> 4;
  int fm7 = fm & 7;

  int srow = tid >> 3;                         // [0,32)
  int scol = (((tid & 7) ^ (srow & 7)) * 8);   // swizzled global col (16B units)
  const ushort* a_gp[4];
  const ushort* b_gp[4];
#pragma unroll
  for (int r = 0; r < 4; r++) {
    a_gp[r] = A + (rowbase + r * 32 + srow) * KTOT + k_base + scol;
    b_gp[r] = BT + ((size_t)e * NTOT + n0 + r * 32 + srow) * KTOT + k_base + scol;
  }

  floatx4 acc[4][4];
#pragma unroll
  for (int i = 0; i < 4; i++)
#pragma unroll
    for (int j = 0; j < 4; j++) acc[i][j] = (floatx4){0.f, 0.f, 0.f, 0.f};

  auto stage = [&](int ki, int buf) {
    int k0 = ki * 64;
    char* al = (char*)As[buf] + wave * 1024;  // wave-uniform base (+ r*4096 per round)
    char* bl = (char*)Bs[buf] + wave * 1024;
#pragma unroll
    for (int r = 0; r < 4; r++) {
      gld_lds16(a_gp[r] + k0, al + r * 4096);
      gld_lds16(b_gp[r] + k0, bl + r * 4096);
    }
  };

  stage(0, 0);
  for (int ki = 0; ki < KITER; ki++) {
    __syncthreads();  // drains DMA(ki); also separates compute(ki-1) from stage(ki+1)
    if (ki + 1 < KITER) stage(ki + 1, (ki + 1) & 1);
    const ushort* Ab = As[ki & 1];
    const ushort* Bb = Bs[ki & 1];
#pragma unroll
    for (int ks = 0; ks < 2; ks++) {
      int c8 = ((ks * 4 + quad) ^ fm7) * 8;  // unswizzle on read
      bf16x8 af[4], bfr[4];
#pragma unroll
      for (int i = 0; i < 4; i++) {
        af[i]  = *(const bf16x8*)(Ab + (mw + i * 16 + fm) * 64 + c8);
        bfr[i] = *(const bf16x8*)(Bb + (nw + i * 16 + fm) * 64 + c8);
      }
#pragma unroll
      for (int mi = 0; mi < 4; mi++)
#pragma unroll
        for (int ni = 0; ni < 4; ni++)
          acc[mi][ni] = __builtin_amdgcn_mfma_f32_16x16x32_bf16(af[mi], bfr[ni], acc[mi][ni], 0, 0, 0);
    }
  }

  // C/D layout: col = lane&15, row = quad*4 + reg (m89/m91 verified)
#pragma unroll
  for (int mi = 0; mi < 4; mi++) {
    int lmb = mt * 128 + mw + mi * 16 + quad * 4;
#pragma unroll
    for (int r = 0; r < 4; r++) {
      int lm = lmb + r;
      if (lm >= ce) continue;
      if (MODE == 1) {
        size_t row = (size_t)e * BCAP + lm;
#pragma unroll
        for (int ni = 0; ni < 4; ni++) {
          int gcol = n0 + nw + ni * 16 + fm;
          float v = acc[mi][ni][r] + bias[e * NTOT + gcol];
          v = v > 0.f ? v : 0.f;
          Hout[row * NTOT + gcol] = f2bf(v);
        }
      } else {
        int t = tokof[e * BCAP + lm];
        float* dst = Pout + (size_t)(bx >> 2) * T_TOK * NTOT + (size_t)t * NTOT;
#pragma unroll
        for (int ni = 0; ni < 4; ni++)
          dst[n0 + nw + ni * 16 + fm] = acc[mi][ni][r];
      }
    }
  }
}

extern "C" void kernel_launch(void* const* d_in, const int* in_sizes, int n_in,
                              void* d_out, int out_size, void* d_ws, size_t ws_size,
                              hipStream_t stream) {
  const float* x    = (const float*)d_in[0];
  const float* cent = (const float*)d_in[1];
  const float* ln_g = (const float*)d_in[2];
  const float* ln_b = (const float*)d_in[3];
  const float* W1   = (const float*)d_in[4];
  const float* b1   = (const float*)d_in[5];
  const float* W2   = (const float*)d_in[6];
  const float* b2   = (const float*)d_in[7];
  float* out = (float*)d_out;

  char* ws = (char*)d_ws;
  size_t off = 0;
  auto alloc = [&](size_t bytes) {
    char* p = ws + off;
    off += (bytes + 255) & ~(size_t)255;
    return p;
  };
  int*    cnt    = (int*)alloc(E_NUM * 4);
  float*  alphav = (float*)alloc(T_TOK * 4);
  int*    eidv   = (int*)alloc(T_TOK * 4);
  int*    tokof  = (int*)alloc((size_t)E_NUM * BCAP * 4);               // 64 KB
  ushort* h0p    = (ushort*)alloc((size_t)E_NUM * BCAP * D_DIM * 2);    // 16.8 MB bf16 buckets
  ushort* H      = (ushort*)alloc((size_t)E_NUM * BCAP * F_DIM * 2);    // 67 MB bf16 buckets
  ushort* W1T    = (ushort*)alloc((size_t)E_NUM * F_DIM * D_DIM * 2);   // 16.8 MB bf16 [E][F][D]
  ushort* W2T    = (ushort*)alloc((size_t)E_NUM * D_DIM * F_DIM * 2);   // 16.8 MB bf16 [E][D][F]
  float*  Part   = (float*)alloc((size_t)4 * T_TOK * D_DIM * 4);        // 16.8 MB f32, token-indexed

  // 1) weight convert/transpose (also zeroes cnt, before front in stream order)
  hipLaunchKernelGGL(convT_kernel, dim3(32, 16, 16), dim3(256), 0, stream,
                     W1, W2, W1T, W2T, cnt);
  // 2) fused router + bucket scatter + LN
  hipLaunchKernelGGL(front_kernel, dim3(T_TOK / 4), dim3(256), 0, stream,
                     x, cent, ln_g, ln_b, cnt, alphav, eidv, tokof, h0p);
  // 3) H = relu(h0 @ W1 + b1): 128x128 tiles, dbuf
  hipLaunchKernelGGL((moe_gemm_kernel<D_DIM, F_DIM, 1>),
                     dim3(F_DIM / 128, BCAP / 128, E_NUM), dim3(256), 0, stream,
                     h0p, W1T, b1, cnt, tokof, H, nullptr);
  // 4) Part[slice] = H @ W2 (raw partials): 128x128 tiles, split-K=4, dbuf
  hipLaunchKernelGGL((moe_gemm_kernel<F_DIM, D_DIM, 2>),
                     dim3(4 * 4, BCAP / 128, E_NUM), dim3(256), 0, stream,
                     H, W2T, nullptr, cnt, tokof, nullptr, Part);
  // 5) out = x + alpha*(sum Part + b2)
  hipLaunchKernelGGL(reduce_kernel, dim3(T_TOK), dim3(128), 0, stream,
                     Part, x, b2, eidv, alphav, out);
}